// Round 14
// baseline (1112.580 us; speedup 1.0000x reference)
//
#include <hip/hip_runtime.h>
#include <hip/hip_bf16.h>
#include <math.h>

typedef __hip_bfloat16 bf16;
typedef short s16x8 __attribute__((ext_vector_type(8)));
typedef float f32x4 __attribute__((ext_vector_type(4)));

#define M_TOK 2048
#define DD    512
#define LSEQ  1024
#define PW    1088   /* 2D + R + 2N */
#define NST   16
#define RR    32
#define DFFW  2048
#define NCH   64
#define CH    16
#define PAD   36
#define NHEAD 50000
#define NHEADP 50176  /* multiple of 256 for the 256x256 head tile */

__device__ __forceinline__ float bf2f(bf16 v) { return __bfloat162float(v); }
__device__ __forceinline__ float siluf(float x) { return x / (1.f + expf(-x)); }

__device__ __forceinline__ s16x8 cvt8(const f32x4& a, const f32x4& b) {
  s16x8 r;
  r[0] = (short)__bfloat16_as_ushort(__float2bfloat16(a[0]));
  r[1] = (short)__bfloat16_as_ushort(__float2bfloat16(a[1]));
  r[2] = (short)__bfloat16_as_ushort(__float2bfloat16(a[2]));
  r[3] = (short)__bfloat16_as_ushort(__float2bfloat16(a[3]));
  r[4] = (short)__bfloat16_as_ushort(__float2bfloat16(b[0]));
  r[5] = (short)__bfloat16_as_ushort(__float2bfloat16(b[1]));
  r[6] = (short)__bfloat16_as_ushort(__float2bfloat16(b[2]));
  r[7] = (short)__bfloat16_as_ushort(__float2bfloat16(b[3]));
  return r;
}

__device__ __forceinline__ void gload16(const bf16* g, bf16* l) {
  __builtin_amdgcn_global_load_lds((const __attribute__((address_space(1))) void*)g,
                                   (__attribute__((address_space(3))) void*)l, 16, 0, 0);
}

__constant__ float c_invn[NST] = {
  -1.f/1, -1.f/2, -1.f/3, -1.f/4, -1.f/5, -1.f/6, -1.f/7, -1.f/8,
  -1.f/9, -1.f/10, -1.f/11, -1.f/12, -1.f/13, -1.f/14, -1.f/15, -1.f/16 };

// ---------------- f32 -> bf16 weight conversion (zero-pad past n_src) ----------------
__global__ __launch_bounds__(256) void k_cvt(
    const float* __restrict__ src, bf16* __restrict__ dst, int n_src, int n_dst)
{
  for (int i = (blockIdx.x * 256 + threadIdx.x) * 8; i < n_dst; i += gridDim.x * 256 * 8) {
    s16x8 v;
    if (i + 8 <= n_src) {
      f32x4 a = *(const f32x4*)(src + i), b = *(const f32x4*)(src + i + 4);
      v = cvt8(a, b);
    } else {
      v = (s16x8){0,0,0,0,0,0,0,0};
    }
    *(s16x8*)((short*)dst + i) = v;
  }
}

// ---------------- time embedding MLP ----------------
__global__ __launch_bounds__(256) void k_te1(
    const int* __restrict__ t, const float* __restrict__ w1, const float* __restrict__ b1,
    float* __restrict__ h1)
{
  __shared__ float semb[2][512];
  int tid = threadIdx.x;
  float t0 = (float)t[0], t1 = (float)t[1];
  {
    int k = tid;
    float f = expf((float)k * (-9.210340371976184f / 255.f));
    semb[0][k]       = sinf(t0 * f);
    semb[0][k + 256] = cosf(t0 * f);
    semb[1][k]       = sinf(t1 * f);
    semb[1][k + 256] = cosf(t1 * f);
  }
  __syncthreads();
  int wave = tid >> 6, lane = tid & 63;
  int j = blockIdx.x * 4 + wave;
  const float* wr = w1 + (size_t)j * 512;
  float s0 = 0.f, s1 = 0.f;
#pragma unroll
  for (int i = 0; i < 8; ++i) {
    int k = lane + (i << 6);
    float wv = wr[k];
    s0 += wv * semb[0][k];
    s1 += wv * semb[1][k];
  }
  for (int o = 32; o; o >>= 1) { s0 += __shfl_down(s0, o); s1 += __shfl_down(s1, o); }
  if (!lane) {
    float bv = b1[j];
    h1[j]        = siluf(s0 + bv);
    h1[2048 + j] = siluf(s1 + bv);
  }
}

__global__ __launch_bounds__(256) void k_te2(
    const float* __restrict__ h1, const float* __restrict__ w2, const float* __restrict__ b2,
    float* __restrict__ te)
{
  __shared__ float sh1[2][2048];
  int tid = threadIdx.x;
  for (int idx = tid; idx < 4096; idx += 256)
    sh1[idx >> 11][idx & 2047] = h1[idx];
  __syncthreads();
  int wave = tid >> 6, lane = tid & 63;
  int d = blockIdx.x * 4 + wave;
  const float* wr = w2 + (size_t)d * 2048;
  float s0 = 0.f, s1 = 0.f;
#pragma unroll
  for (int i = 0; i < 32; ++i) {
    int k = lane + (i << 6);
    float wv = wr[k];
    s0 += wv * sh1[0][k];
    s1 += wv * sh1[1][k];
  }
  for (int o = 32; o; o >>= 1) { s0 += __shfl_down(s0, o); s1 += __shfl_down(s1, o); }
  if (!lane) {
    float bv = b2[d];
    te[d]       = s0 + bv;
    te[512 + d] = s1 + bv;
  }
}

// ---------------- token embed + time embed add ----------------
__global__ __launch_bounds__(256) void k_embed(
    const int* __restrict__ x_t, const float* __restrict__ tok,
    const float* __restrict__ te, float* __restrict__ x)
{
  int m = blockIdx.x;
  int b = m >> 10;
  int row = x_t[m];
  const float* src = tok + (size_t)row * DD;
  for (int d = threadIdx.x; d < DD; d += 256)
    x[(size_t)m * DD + d] = src[d] + te[b * DD + d];
}

// ---------------- LayerNorm ----------------
__global__ __launch_bounds__(256) void k_layernorm(
    const float* __restrict__ x, const float* __restrict__ g, const float* __restrict__ bb,
    bf16* __restrict__ out)
{
  int m = blockIdx.x;
  const float* xr = x + (size_t)m * DD;
  float2 v = ((const float2*)xr)[threadIdx.x];
  float s = v.x + v.y, ss = v.x * v.x + v.y * v.y;
  for (int o = 32; o; o >>= 1) { s += __shfl_down(s, o); ss += __shfl_down(ss, o); }
  __shared__ float ps[4], pss[4];
  int wave = threadIdx.x >> 6, lane = threadIdx.x & 63;
  if (!lane) { ps[wave] = s; pss[wave] = ss; }
  __syncthreads();
  s = ps[0] + ps[1] + ps[2] + ps[3];
  ss = pss[0] + pss[1] + pss[2] + pss[3];
  float mu = s * (1.f / DD);
  float var = ss * (1.f / DD) - mu * mu;
  float inv = rsqrtf(var + 1e-5f);
  int d = threadIdx.x * 2;
  out[(size_t)m * DD + d]     = __float2bfloat16((v.x - mu) * inv * g[d]     + bb[d]);
  out[(size_t)m * DD + d + 1] = __float2bfloat16((v.y - mu) * inv * g[d + 1] + bb[d + 1]);
}

// ---------------- fused conv+dt+local-scan (pass 1) ----------------
__global__ __launch_bounds__(128) void k_scan1f(
    const float* __restrict__ proj, const float* __restrict__ convw,
    const float* __restrict__ dtw, const float* __restrict__ dtb,
    float* __restrict__ ubuf, float* __restrict__ yloc,
    float* __restrict__ Ebuf, float* __restrict__ Aprod, float* __restrict__ hend)
{
  int d = (blockIdx.x << 7) + threadIdx.x;
  int c = blockIdx.y, b = blockIdx.z;
  int m0 = b * LSEQ + c * CH;
  __shared__ float sBC[CH][32];
  __shared__ float sDT[CH][32];
  for (int idx = threadIdx.x; idx < CH * 32; idx += 128) {
    int l = idx >> 5, j = idx & 31;
    sBC[l][j] = proj[(size_t)(m0 + l) * PW + 2 * DD + RR + j];
    sDT[l][j] = proj[(size_t)(m0 + l) * PW + 2 * DD + j];
  }
  __syncthreads();
  float cw0 = convw[d * 4], cw1 = convw[d * 4 + 1], cw2 = convw[d * 4 + 2], cw3 = convw[d * 4 + 3];
  float dtbd = dtb[d];
  f32x4 wr[8];
#pragma unroll
  for (int i = 0; i < 8; ++i) wr[i] = *(const f32x4*)(dtw + (size_t)d * RR + i * 4);
  float w0 = 0.f, w1 = 0.f, w2 = 0.f;
  {
    int l0 = c * CH;
    if (l0 >= 3) w0 = proj[(size_t)(m0 - 3) * PW + d];
    if (l0 >= 2) w1 = proj[(size_t)(m0 - 2) * PW + d];
    if (l0 >= 1) w2 = proj[(size_t)(m0 - 1) * PW + d];
  }
  float h[NST];
#pragma unroll
  for (int n = 0; n < NST; ++n) h[n] = 0.f;
  float S = 0.f;
  for (int l = 0; l < CH; ++l) {
    size_t m = (size_t)(m0 + l);
    float xc = proj[m * PW + d];
    float cv = w0 * cw0 + w1 * cw1 + w2 * cw2 + xc * cw3;
    w0 = w1; w1 = w2; w2 = xc;
    float uv = siluf(cv);
    ubuf[m * DD + d] = uv;
    float s = dtbd;
#pragma unroll
    for (int i = 0; i < 8; ++i) {
      f32x4 q = *(const f32x4*)&sDT[l][i * 4];
      s += q[0] * wr[i][0] + q[1] * wr[i][1] + q[2] * wr[i][2] + q[3] * wr[i][3];
    }
    float dtv = (s > 0.f) ? (s + log1pf(expf(-s))) : log1pf(expf(s));
    float e1 = expf(-dtv);
    S += dtv;
    Ebuf[m * DD + d] = expf(-S);
    float p = 1.f, acc = 0.f;
#pragma unroll
    for (int n = 0; n < NST; ++n) {
      p *= e1;
      float bu = (p - 1.f) * c_invn[n] * sBC[l][n] * uv;
      h[n] = p * h[n] + bu;
      acc += sBC[l][16 + n] * h[n];
    }
    yloc[m * DD + d] = acc;
  }
  float Ec = expf(-S);
  float p = 1.f;
  size_t base = ((size_t)(b * NCH + c) * NST) * DD + d;
#pragma unroll
  for (int n = 0; n < NST; ++n) {
    p *= Ec;
    Aprod[base + (size_t)n * DD] = p;
    hend [base + (size_t)n * DD] = h[n];
  }
}

// ---------------- scan pass 2: wave-parallel prefix over chunks ----------------
__global__ __launch_bounds__(256) void k_scan2w(
    const float* __restrict__ Aprod, const float* __restrict__ hend, float* __restrict__ h0)
{
  int wave = threadIdx.x >> 6, lane = threadIdx.x & 63;
  int chain = blockIdx.x * 4 + wave;          // b*8192 + n*512 + d
  int d = chain & 511;
  int n = (chain >> 9) & 15;
  int b = chain >> 13;
  size_t o = ((size_t)((b * NCH + lane) * NST + n)) * DD + d;
  float A = Aprod[o], h = hend[o];
#pragma unroll
  for (int off = 1; off < 64; off <<= 1) {
    float Ap = __shfl_up(A, off);
    float hp = __shfl_up(h, off);
    if (lane >= off) { h = A * hp + h; A = A * Ap; }
  }
  float hprev = __shfl_up(h, 1);
  h0[o] = (lane == 0) ? 0.f : hprev;
}

// ---------------- scan pass 3 + gate ----------------
__global__ __launch_bounds__(128) void k_scan3(
    const float* __restrict__ proj, const float* __restrict__ u,
    const float* __restrict__ yloc, const float* __restrict__ Ebuf,
    const float* __restrict__ h0, const float* __restrict__ Dp, bf16* __restrict__ out)
{
  int d = (blockIdx.x << 7) + threadIdx.x;
  int c = blockIdx.y, b = blockIdx.z;
  int m0 = b * LSEQ + c * CH;
  __shared__ float sC[CH][NST];
  for (int idx = threadIdx.x; idx < CH * NST; idx += 128)
    sC[idx >> 4][idx & 15] = proj[(size_t)(m0 + (idx >> 4)) * PW + 2 * DD + RR + NST + (idx & 15)];
  __syncthreads();
  float hh[NST];
  size_t base = ((size_t)(b * NCH + c) * NST) * DD + d;
#pragma unroll
  for (int n = 0; n < NST; ++n) hh[n] = h0[base + (size_t)n * DD];
  float dpv = Dp[d];
  for (int l = 0; l < CH; ++l) {
    size_t m = (size_t)(m0 + l);
    float E = Ebuf[m * DD + d];
    float p = 1.f, corr = 0.f;
#pragma unroll
    for (int n = 0; n < NST; ++n) {
      p *= E;
      corr += sC[l][n] * p * hh[n];
    }
    float y = yloc[m * DD + d] + corr;
    float z = proj[m * PW + DD + d];
    float v = (y + u[m * DD + d] * dpv) * siluf(z);
    out[m * DD + d] = __float2bfloat16(v);
  }
}

// ========= bf16 GEMMs: global_load_lds, BK=64 two-chunk staging =========
// 64x64 tile, BK=64: 4 gloads + 16 MFMA/wave per barrier drain. K%64==0.
template<int ACT, bool BF16OUT, bool RES, bool BIAS>
__global__ __launch_bounds__(256) void gemm_bb64k(
    const bf16* __restrict__ A, const bf16* __restrict__ B,
    const float* __restrict__ bias, const float* __restrict__ res,
    void* __restrict__ Cout, int N, int K)
{
  __shared__ bf16 sA[2][64 * 32];
  __shared__ bf16 sB[2][64 * 32];
  int flat = blockIdx.y * gridDim.x + blockIdx.x;
  int qq = (gridDim.x * gridDim.y) >> 3;
  int s = (flat & 7) * qq + (flat >> 3);
  int bm = (s % gridDim.x) * 64;
  int bn = (s / gridDim.x) * 64;
  int tid = threadIdx.x;
  int wave = tid >> 6, lane = tid & 63;
  int wm = (wave >> 1) << 5, wn = (wave & 1) << 5;
  int r = lane & 15, q = lane >> 4;
  int srow = (wave << 4) + (lane >> 2);
  int scol = (lane & 3) << 3;
  const bf16* pA = A + (size_t)(bm + srow) * K + scol;
  const bf16* pB = B + (size_t)(bn + srow) * K + scol;
  int lofs = (wave << 4) << 5;

  f32x4 acc[2][2];
#pragma unroll
  for (int i = 0; i < 2; ++i)
#pragma unroll
    for (int j = 0; j < 2; ++j) acc[i][j] = (f32x4){0.f, 0.f, 0.f, 0.f};

  for (int k0 = 0; k0 < K; k0 += 64) {
    gload16(pA,      sA[0] + lofs);
    gload16(pA + 32, sA[1] + lofs);
    gload16(pB,      sB[0] + lofs);
    gload16(pB + 32, sB[1] + lofs);
    pA += 64; pB += 64;
    __syncthreads();
#pragma unroll
    for (int kk = 0; kk < 2; ++kk) {
      s16x8 af[2], bg[2];
#pragma unroll
      for (int i = 0; i < 2; ++i) af[i] = *(s16x8*)&sA[kk][((wm + i * 16 + r) << 5) + (q << 3)];
#pragma unroll
      for (int j = 0; j < 2; ++j) bg[j] = *(s16x8*)&sB[kk][((wn + j * 16 + r) << 5) + (q << 3)];
#pragma unroll
      for (int i = 0; i < 2; ++i)
#pragma unroll
        for (int j = 0; j < 2; ++j)
          acc[i][j] = __builtin_amdgcn_mfma_f32_16x16x32_bf16(af[i], bg[j], acc[i][j], 0, 0, 0);
    }
    __syncthreads();
  }

#pragma unroll
  for (int i = 0; i < 2; ++i)
#pragma unroll
    for (int j = 0; j < 2; ++j) {
      int n = bn + wn + j * 16 + r;
#pragma unroll
      for (int e = 0; e < 4; ++e) {
        int m = bm + wm + i * 16 + (q << 2) + e;
        float v = acc[i][j][e];
        if (BIAS) v += bias[n];
        if (ACT == 1) v = 0.5f * v * (1.f + erff(v * 0.70710678118f));
        if (RES) v += res[(size_t)m * N + n];
        if (BF16OUT) ((bf16*)Cout)[(size_t)m * N + n] = __float2bfloat16(v);
        else         ((float*)Cout)[(size_t)m * N + n] = v;
      }
    }
}

// ======== head: 256x256 tile, 512 thr, BK=32 double-buffered 2-phase ========
// 8 waves (2M x 4N), wave owns 128x64 (acc[8][4]); stage next chunk BEFORE
// compute so the barrier's vmcnt(0) drain is covered by 32 MFMA. LDS 64KB.
// grid (M/256, NP/256), bijective XCD swizzle; C stride/bounds = true N.
template<bool BIAS>
__global__ __launch_bounds__(512) void gemm_bhead256(
    const bf16* __restrict__ A, const bf16* __restrict__ B,
    const float* __restrict__ bias, float* __restrict__ C, int N, int K)
{
  __shared__ bf16 sA[2][256 * 32];
  __shared__ bf16 sB[2][256 * 32];
  int flat = blockIdx.y * gridDim.x + blockIdx.x;
  int qq = (gridDim.x * gridDim.y) >> 3;
  int s = (flat & 7) * qq + (flat >> 3);
  int bm = (s % gridDim.x) * 256;
  int bn = (s / gridDim.x) * 256;
  int tid = threadIdx.x;
  int wave = tid >> 6, lane = tid & 63;
  int wm = (wave >> 2) << 7;          // 0 or 128
  int wn = (wave & 3) << 6;           // 0,64,128,192
  int r = lane & 15, q = lane >> 4;
  int srow = (wave << 4) + (lane >> 2);   // 0..127
  int scol = (lane & 3) << 3;
  const bf16* pA = A + (size_t)(bm + srow) * K + scol;
  const bf16* pB = B + (size_t)(bn + srow) * K + scol;
  int lofs = (wave << 4) << 5;        // wave-uniform LDS elem offset

  f32x4 acc[8][4];
#pragma unroll
  for (int i = 0; i < 8; ++i)
#pragma unroll
    for (int j = 0; j < 4; ++j) acc[i][j] = (f32x4){0.f, 0.f, 0.f, 0.f};

  // prologue: chunk 0 -> buffer 0
  gload16(pA,                   sA[0] + lofs);
  gload16(pA + (size_t)128 * K, sA[0] + lofs + 128 * 32);
  gload16(pB,                   sB[0] + lofs);
  gload16(pB + (size_t)128 * K, sB[0] + lofs + 128 * 32);
  pA += 32; pB += 32;
  __syncthreads();

  int cur = 0;
  for (int k0 = 0; k0 < K; k0 += 32) {
    if (k0 + 32 < K) {                // issue next chunk BEFORE compute
      gload16(pA,                   sA[cur ^ 1] + lofs);
      gload16(pA + (size_t)128 * K, sA[cur ^ 1] + lofs + 128 * 32);
      gload16(pB,                   sB[cur ^ 1] + lofs);
      gload16(pB + (size_t)128 * K, sB[cur ^ 1] + lofs + 128 * 32);
      pA += 32; pB += 32;
    }
    s16x8 bg[4];
#pragma unroll
    for (int j = 0; j < 4; ++j) bg[j] = *(s16x8*)&sB[cur][((wn + j * 16 + r) << 5) + (q << 3)];
#pragma unroll
    for (int i = 0; i < 8; ++i) {
      s16x8 af = *(s16x8*)&sA[cur][((wm + i * 16 + r) << 5) + (q << 3)];
#pragma unroll
      for (int j = 0; j < 4; ++j)
        acc[i][j] = __builtin_amdgcn_mfma_f32_16x16x32_bf16(af, bg[j], acc[i][j], 0, 0, 0);
    }
    __syncthreads();                  // drains vmcnt(0): next buffer staged
    cur ^= 1;
  }

#pragma unroll
  for (int i = 0; i < 8; ++i)
#pragma unroll
    for (int j = 0; j < 4; ++j) {
      int n = bn + wn + j * 16 + r;
      if (n >= N) continue;
#pragma unroll
      for (int e = 0; e < 4; ++e) {
        int m = bm + wm + i * 16 + (q << 2) + e;
        float v = acc[i][j][e];
        if (BIAS) v += bias[n];
        C[(size_t)m * N + n] = v;
      }
    }
}

// ================= fallback f32-weight GEMMs =================
template<int ACT, bool BF16OUT, bool RES, bool BIAS, bool SWZ>
__global__ __launch_bounds__(256) void gemm_abt(
    const bf16* __restrict__ A, const float* __restrict__ B,
    const float* __restrict__ bias, const float* __restrict__ res,
    void* __restrict__ Cout, int N, int K)
{
  __shared__ bf16 sA[128][PAD];
  __shared__ bf16 sB[128][PAD];
  int bn, bm;
  if (SWZ) {
    int flat = blockIdx.y * gridDim.x + blockIdx.x;
    int q = (gridDim.x * gridDim.y) >> 3;
    int s = (flat & 7) * q + (flat >> 3);
    bm = (s % gridDim.x) * 128;
    bn = (s / gridDim.x) * 128;
  } else {
    bn = blockIdx.x * 128;
    bm = blockIdx.y * 128;
  }
  int tid = threadIdx.x;
  int wave = tid >> 6, lane = tid & 63;
  int wm = (wave >> 1) << 6, wn = (wave & 1) << 6;
  int r = lane & 15, q = lane >> 4;
  int ldr = tid >> 2;
  int ldc = (tid & 3) << 3;
  f32x4 acc[4][4];
#pragma unroll
  for (int i = 0; i < 4; ++i)
#pragma unroll
    for (int j = 0; j < 4; ++j) acc[i][j] = (f32x4){0.f, 0.f, 0.f, 0.f};
  s16x8 pa[2];
  f32x4 pb[2][2];
#define GLOAD(k0)                                                              \
  {                                                                            \
    _Pragma("unroll")                                                          \
    for (int h = 0; h < 2; ++h) {                                              \
      int row = ldr + (h << 6);                                                \
      pa[h] = *(const s16x8*)(A + (size_t)(bm + row) * K + (k0) + ldc);        \
      int nrow = bn + row;                                                     \
      if (nrow < N) {                                                          \
        const float* src = B + (size_t)nrow * K + (k0) + ldc;                  \
        pb[h][0] = *(const f32x4*)src;                                         \
        pb[h][1] = *(const f32x4*)(src + 4);                                   \
      } else {                                                                 \
        pb[h][0] = (f32x4){0.f,0.f,0.f,0.f};                                   \
        pb[h][1] = (f32x4){0.f,0.f,0.f,0.f};                                   \
      }                                                                        \
    }                                                                          \
  }
  GLOAD(0);
  for (int k0 = 0; k0 < K; k0 += 32) {
#pragma unroll
    for (int h = 0; h < 2; ++h) {
      int row = ldr + (h << 6);
      *(s16x8*)&sA[row][ldc] = pa[h];
      *(s16x8*)&sB[row][ldc] = cvt8(pb[h][0], pb[h][1]);
    }
    __syncthreads();
    if (k0 + 32 < K) GLOAD(k0 + 32);
    s16x8 af[4], bg[4];
#pragma unroll
    for (int i = 0; i < 4; ++i) af[i] = *(s16x8*)&sA[wm + i * 16 + r][q << 3];
#pragma unroll
    for (int j = 0; j < 4; ++j) bg[j] = *(s16x8*)&sB[wn + j * 16 + r][q << 3];
#pragma unroll
    for (int i = 0; i < 4; ++i)
#pragma unroll
      for (int j = 0; j < 4; ++j)
        acc[i][j] = __builtin_amdgcn_mfma_f32_16x16x32_bf16(af[i], bg[j], acc[i][j], 0, 0, 0);
    __syncthreads();
  }
#undef GLOAD
#pragma unroll
  for (int i = 0; i < 4; ++i)
#pragma unroll
    for (int j = 0; j < 4; ++j) {
      int n = bn + wn + j * 16 + r;
      if (n >= N) continue;
#pragma unroll
      for (int e = 0; e < 4; ++e) {
        int m = bm + wm + i * 16 + (q << 2) + e;
        float v = acc[i][j][e];
        if (BIAS) v += bias[n];
        if (ACT == 1) v = 0.5f * v * (1.f + erff(v * 0.70710678118f));
        if (RES) v += res[(size_t)m * N + n];
        if (BF16OUT) ((bf16*)Cout)[(size_t)m * N + n] = __float2bfloat16(v);
        else         ((float*)Cout)[(size_t)m * N + n] = v;
      }
    }
}

template<int ACT, bool BF16OUT, bool RES, bool BIAS>
__global__ __launch_bounds__(256) void gemm64(
    const bf16* __restrict__ A, const float* __restrict__ B,
    const float* __restrict__ bias, const float* __restrict__ res,
    void* __restrict__ Cout, int N, int K)
{
  __shared__ bf16 sA[64][PAD];
  __shared__ bf16 sB[64][PAD];
  int bn = blockIdx.x * 64;
  int bm = blockIdx.y * 64;
  int tid = threadIdx.x;
  int wave = tid >> 6, lane = tid & 63;
  int wm = (wave >> 1) << 5, wn = (wave & 1) << 5;
  int r = lane & 15, q = lane >> 4;
  int ldr = tid >> 2;
  int ldc = (tid & 3) << 3;
  f32x4 acc[2][2];
#pragma unroll
  for (int i = 0; i < 2; ++i)
#pragma unroll
    for (int j = 0; j < 2; ++j) acc[i][j] = (f32x4){0.f, 0.f, 0.f, 0.f};
  s16x8 pa;
  f32x4 pb[2];
#define GLOAD64(k0)                                                            \
  {                                                                            \
    pa = *(const s16x8*)(A + (size_t)(bm + ldr) * K + (k0) + ldc);             \
    const float* src = B + (size_t)(bn + ldr) * K + (k0) + ldc;                \
    pb[0] = *(const f32x4*)src;                                                \
    pb[1] = *(const f32x4*)(src + 4);                                          \
  }
  GLOAD64(0);
  for (int k0 = 0; k0 < K; k0 += 32) {
    *(s16x8*)&sA[ldr][ldc] = pa;
    *(s16x8*)&sB[ldr][ldc] = cvt8(pb[0], pb[1]);
    __syncthreads();
    if (k0 + 32 < K) GLOAD64(k0 + 32);
    s16x8 af[2], bg[2];
#pragma unroll
    for (int i = 0; i < 2; ++i) af[i] = *(s16x8*)&sA[wm + i * 16 + r][q << 3];
#pragma unroll
    for (int j = 0; j < 2; ++j) bg[j] = *(s16x8*)&sB[wn + j * 16 + r][q << 3];
#pragma unroll
    for (int i = 0; i < 2; ++i)
#pragma unroll
      for (int j = 0; j < 2; ++j)
        acc[i][j] = __builtin_amdgcn_mfma_f32_16x16x32_bf16(af[i], bg[j], acc[i][j], 0, 0, 0);
    __syncthreads();
  }
#undef GLOAD64
#pragma unroll
  for (int i = 0; i < 2; ++i)
#pragma unroll
    for (int j = 0; j < 2; ++j) {
      int n = bn + wn + j * 16 + r;
#pragma unroll
      for (int e = 0; e < 4; ++e) {
        int m = bm + wm + i * 16 + (q << 2) + e;
        float v = acc[i][j][e];
        if (BIAS) v += bias[n];
        if (ACT == 1) v = 0.5f * v * (1.f + erff(v * 0.70710678118f));
        if (RES) v += res[(size_t)m * N + n];
        if (BF16OUT) ((bf16*)Cout)[(size_t)m * N + n] = __float2bfloat16(v);
        else         ((float*)Cout)[(size_t)m * N + n] = v;
      }
    }
}

// ---------------- launch ----------------
extern "C" void kernel_launch(void* const* d_in, const int* in_sizes, int n_in,
                              void* d_out, int out_size, void* d_ws, size_t ws_size,
                              hipStream_t stream) {
  const int*   x_t     = (const int*)d_in[0];
  const int*   t       = (const int*)d_in[1];
  const float* tok_emb = (const float*)d_in[2];
  const float* tmlp_w1 = (const float*)d_in[3];
  const float* tmlp_b1 = (const float*)d_in[4];
  const float* tmlp_w2 = (const float*)d_in[5];
  const float* tmlp_b2 = (const float*)d_in[6];
  const float* ln1_g   = (const float*)d_in[7];
  const float* ln1_b   = (const float*)d_in[8];
  const float* in_w    = (const float*)d_in[9];
  const float* conv_w  = (const float*)d_in[10];
  const float* dt_w    = (const float*)d_in[11];
  const float* dt_b    = (const float*)d_in[12];
  const float* D_p     = (const float*)d_in[13];
  const float* out_w   = (const float*)d_in[14];
  const float* ln2_g   = (const float*)d_in[15];
  const float* ln2_b   = (const float*)d_in[16];
  const float* mlp_w1  = (const float*)d_in[17];
  const float* mlp_b1  = (const float*)d_in[18];
  const float* mlp_w2  = (const float*)d_in[19];
  const float* mlp_b2  = (const float*)d_in[20];
  const float* lno_g   = (const float*)d_in[21];
  const float* lno_b   = (const float*)d_in[22];
  const float* head_w  = (const float*)d_in[23];
  const float* head_b  = (const float*)d_in[24];

  char* w = (char*)d_ws;
  float* te    = (float*)w;  w += 4096;
  float* h1t   = (float*)w;  w += 16384;
  float* x     = (float*)w;  w += (size_t)M_TOK * DD * 4;
  bf16*  aIn   = (bf16*)w;   w += (size_t)M_TOK * DD * 2;
  float* proj  = (float*)w;  w += (size_t)M_TOK * PW * 4;
  float* ubuf  = (float*)w;  w += (size_t)M_TOK * DD * 4;
  float* ybuf  = (float*)w;  w += (size_t)M_TOK * DD * 4;
  float* Ebuf  = (float*)w;  w += (size_t)M_TOK * DD * 4;
  float* Aprod = (float*)w;  w += (size_t)2 * NCH * NST * DD * 4;
  float* hend  = (float*)w;  w += (size_t)2 * NCH * NST * DD * 4;
  float* h0    = (float*)w;  w += (size_t)2 * NCH * NST * DD * 4;
  bf16*  gbuf  = (bf16*)proj;
  bf16* bw_in   = (bf16*)w;  w += (size_t)6 * PW * DD * 2;
  bf16* bw_out  = (bf16*)w;  w += (size_t)6 * DD * DD * 2;
  bf16* bw_m1   = (bf16*)w;  w += (size_t)6 * DFFW * DD * 2;
  bf16* bw_m2   = (bf16*)w;  w += (size_t)6 * DD * DFFW * 2;
  bf16* bw_head = (bf16*)w;  w += (size_t)NHEADP * DD * 2;
  bool fast = ((size_t)(w - (char*)d_ws) <= ws_size);

  if (fast) {
    k_cvt<<<1024, 256, 0, stream>>>(in_w,   bw_in,   6 * PW * DD,   6 * PW * DD);
    k_cvt<<<1024, 256, 0, stream>>>(out_w,  bw_out,  6 * DD * DD,   6 * DD * DD);
    k_cvt<<<1024, 256, 0, stream>>>(mlp_w1, bw_m1,   6 * DFFW * DD, 6 * DFFW * DD);
    k_cvt<<<1024, 256, 0, stream>>>(mlp_w2, bw_m2,   6 * DD * DFFW, 6 * DD * DFFW);
    k_cvt<<<2048, 256, 0, stream>>>(head_w, bw_head, NHEAD * DD,    NHEADP * DD);
  }

  k_te1<<<512, 256, 0, stream>>>(t, tmlp_w1, tmlp_b1, h1t);
  k_te2<<<128, 256, 0, stream>>>(h1t, tmlp_w2, tmlp_b2, te);
  k_embed<<<M_TOK, 256, 0, stream>>>(x_t, tok_emb, te, x);

  for (int i = 0; i < 6; ++i) {
    const float* cw_i   = conv_w + (size_t)i * DD * 4;
    const float* dtw_i  = dt_w   + (size_t)i * DD * RR;
    const float* dtb_i  = dt_b   + (size_t)i * DD;
    const float* dp_i   = D_p    + (size_t)i * DD;
    const float* m1b_i  = mlp_b1 + (size_t)i * DFFW;
    const float* m2b_i  = mlp_b2 + (size_t)i * DD;

    k_layernorm<<<M_TOK, 256, 0, stream>>>(x, ln1_g + i * DD, ln1_b + i * DD, aIn);
    if (fast)
      gemm_bb64k<0,false,false,false><<<dim3(M_TOK / 64, PW / 64), 256, 0, stream>>>(
          aIn, bw_in + (size_t)i * PW * DD, nullptr, nullptr, proj, PW, DD);
    else
      gemm64<0,false,false,false><<<dim3(PW / 64, M_TOK / 64), 256, 0, stream>>>(
          aIn, in_w + (size_t)i * PW * DD, nullptr, nullptr, proj, PW, DD);
    k_scan1f<<<dim3(4, NCH, 2), 128, 0, stream>>>(proj, cw_i, dtw_i, dtb_i,
                                                  ubuf, ybuf, Ebuf, Aprod, hend);
    k_scan2w<<<2 * NST * DD / 4, 256, 0, stream>>>(Aprod, hend, h0);
    k_scan3<<<dim3(4, NCH, 2), 128, 0, stream>>>(proj, ubuf, ybuf, Ebuf, h0, dp_i, aIn);
    if (fast) {
      gemm_bb64k<0,false,true,false><<<dim3(M_TOK / 64, DD / 64), 256, 0, stream>>>(
          aIn, bw_out + (size_t)i * DD * DD, nullptr, x, x, DD, DD);
      k_layernorm<<<M_TOK, 256, 0, stream>>>(x, ln2_g + i * DD, ln2_b + i * DD, aIn);
      gemm_bb64k<1,true,false,true><<<dim3(M_TOK / 64, DFFW / 64), 256, 0, stream>>>(
          aIn, bw_m1 + (size_t)i * DFFW * DD, m1b_i, nullptr, gbuf, DFFW, DD);
      gemm_bb64k<0,false,true,true><<<dim3(M_TOK / 64, DD / 64), 256, 0, stream>>>(
          gbuf, bw_m2 + (size_t)i * DD * DFFW, m2b_i, x, x, DD, DFFW);
    } else {
      gemm64<0,false,true,false><<<dim3(DD / 64, M_TOK / 64), 256, 0, stream>>>(
          aIn, out_w + (size_t)i * DD * DD, nullptr, x, x, DD, DD);
      k_layernorm<<<M_TOK, 256, 0, stream>>>(x, ln2_g + i * DD, ln2_b + i * DD, aIn);
      gemm64<1,true,false,true><<<dim3(DFFW / 64, M_TOK / 64), 256, 0, stream>>>(
          aIn, mlp_w1 + (size_t)i * DFFW * DD, m1b_i, nullptr, gbuf, DFFW, DD);
      gemm64<0,false,true,true><<<dim3(DD / 64, M_TOK / 64), 256, 0, stream>>>(
          gbuf, mlp_w2 + (size_t)i * DD * DFFW, m2b_i, x, x, DD, DFFW);
    }
  }

  k_layernorm<<<M_TOK, 256, 0, stream>>>(x, lno_g, lno_b, aIn);
  if (fast)
    gemm_bhead256<true><<<dim3(M_TOK / 256, NHEADP / 256), 512, 0, stream>>>(
        aIn, bw_head, head_b, (float*)d_out, NHEAD, DD);
  else
    gemm_abt<0,false,false,true,true><<<dim3(M_TOK / 128, (NHEAD + 127) / 128), 256, 0, stream>>>(
        aIn, head_w, head_b, nullptr, d_out, NHEAD, DD);
}

// Round 15
// 1080.562 us; speedup vs baseline: 1.0296x; 1.0296x over previous
//
#include <hip/hip_runtime.h>
#include <hip/hip_bf16.h>
#include <math.h>

typedef __hip_bfloat16 bf16;
typedef short s16x8 __attribute__((ext_vector_type(8)));
typedef float f32x4 __attribute__((ext_vector_type(4)));

#define M_TOK 2048
#define DD    512
#define LSEQ  1024
#define PW    1088   /* 2D + R + 2N */
#define NST   16
#define RR    32
#define DFFW  2048
#define NCH   64
#define CH    16
#define PAD   36
#define NHEAD 50000
#define NHEADP 50048  /* multiple of 128 for the 128x128 head tile */

__device__ __forceinline__ float bf2f(bf16 v) { return __bfloat162float(v); }
__device__ __forceinline__ float siluf(float x) { return x / (1.f + expf(-x)); }

__device__ __forceinline__ s16x8 cvt8(const f32x4& a, const f32x4& b) {
  s16x8 r;
  r[0] = (short)__bfloat16_as_ushort(__float2bfloat16(a[0]));
  r[1] = (short)__bfloat16_as_ushort(__float2bfloat16(a[1]));
  r[2] = (short)__bfloat16_as_ushort(__float2bfloat16(a[2]));
  r[3] = (short)__bfloat16_as_ushort(__float2bfloat16(a[3]));
  r[4] = (short)__bfloat16_as_ushort(__float2bfloat16(b[0]));
  r[5] = (short)__bfloat16_as_ushort(__float2bfloat16(b[1]));
  r[6] = (short)__bfloat16_as_ushort(__float2bfloat16(b[2]));
  r[7] = (short)__bfloat16_as_ushort(__float2bfloat16(b[3]));
  return r;
}

__device__ __forceinline__ void gload16(const bf16* g, bf16* l) {
  __builtin_amdgcn_global_load_lds((const __attribute__((address_space(1))) void*)g,
                                   (__attribute__((address_space(3))) void*)l, 16, 0, 0);
}

__constant__ float c_invn[NST] = {
  -1.f/1, -1.f/2, -1.f/3, -1.f/4, -1.f/5, -1.f/6, -1.f/7, -1.f/8,
  -1.f/9, -1.f/10, -1.f/11, -1.f/12, -1.f/13, -1.f/14, -1.f/15, -1.f/16 };

// ---------------- f32 -> bf16 weight conversion (zero-pad past n_src) ----------------
__global__ __launch_bounds__(256) void k_cvt(
    const float* __restrict__ src, bf16* __restrict__ dst, int n_src, int n_dst)
{
  for (int i = (blockIdx.x * 256 + threadIdx.x) * 8; i < n_dst; i += gridDim.x * 256 * 8) {
    s16x8 v;
    if (i + 8 <= n_src) {
      f32x4 a = *(const f32x4*)(src + i), b = *(const f32x4*)(src + i + 4);
      v = cvt8(a, b);
    } else {
      v = (s16x8){0,0,0,0,0,0,0,0};
    }
    *(s16x8*)((short*)dst + i) = v;
  }
}

// ---------------- time embedding MLP ----------------
__global__ __launch_bounds__(256) void k_te1(
    const int* __restrict__ t, const float* __restrict__ w1, const float* __restrict__ b1,
    float* __restrict__ h1)
{
  __shared__ float semb[2][512];
  int tid = threadIdx.x;
  float t0 = (float)t[0], t1 = (float)t[1];
  {
    int k = tid;
    float f = expf((float)k * (-9.210340371976184f / 255.f));
    semb[0][k]       = sinf(t0 * f);
    semb[0][k + 256] = cosf(t0 * f);
    semb[1][k]       = sinf(t1 * f);
    semb[1][k + 256] = cosf(t1 * f);
  }
  __syncthreads();
  int wave = tid >> 6, lane = tid & 63;
  int j = blockIdx.x * 4 + wave;
  const float* wr = w1 + (size_t)j * 512;
  float s0 = 0.f, s1 = 0.f;
#pragma unroll
  for (int i = 0; i < 8; ++i) {
    int k = lane + (i << 6);
    float wv = wr[k];
    s0 += wv * semb[0][k];
    s1 += wv * semb[1][k];
  }
  for (int o = 32; o; o >>= 1) { s0 += __shfl_down(s0, o); s1 += __shfl_down(s1, o); }
  if (!lane) {
    float bv = b1[j];
    h1[j]        = siluf(s0 + bv);
    h1[2048 + j] = siluf(s1 + bv);
  }
}

__global__ __launch_bounds__(256) void k_te2(
    const float* __restrict__ h1, const float* __restrict__ w2, const float* __restrict__ b2,
    float* __restrict__ te)
{
  __shared__ float sh1[2][2048];
  int tid = threadIdx.x;
  for (int idx = tid; idx < 4096; idx += 256)
    sh1[idx >> 11][idx & 2047] = h1[idx];
  __syncthreads();
  int wave = tid >> 6, lane = tid & 63;
  int d = blockIdx.x * 4 + wave;
  const float* wr = w2 + (size_t)d * 2048;
  float s0 = 0.f, s1 = 0.f;
#pragma unroll
  for (int i = 0; i < 32; ++i) {
    int k = lane + (i << 6);
    float wv = wr[k];
    s0 += wv * sh1[0][k];
    s1 += wv * sh1[1][k];
  }
  for (int o = 32; o; o >>= 1) { s0 += __shfl_down(s0, o); s1 += __shfl_down(s1, o); }
  if (!lane) {
    float bv = b2[d];
    te[d]       = s0 + bv;
    te[512 + d] = s1 + bv;
  }
}

// ---------------- token embed + time embed add ----------------
__global__ __launch_bounds__(256) void k_embed(
    const int* __restrict__ x_t, const float* __restrict__ tok,
    const float* __restrict__ te, float* __restrict__ x)
{
  int m = blockIdx.x;
  int b = m >> 10;
  int row = x_t[m];
  const float* src = tok + (size_t)row * DD;
  for (int d = threadIdx.x; d < DD; d += 256)
    x[(size_t)m * DD + d] = src[d] + te[b * DD + d];
}

// ---------------- LayerNorm ----------------
__global__ __launch_bounds__(256) void k_layernorm(
    const float* __restrict__ x, const float* __restrict__ g, const float* __restrict__ bb,
    bf16* __restrict__ out)
{
  int m = blockIdx.x;
  const float* xr = x + (size_t)m * DD;
  float2 v = ((const float2*)xr)[threadIdx.x];
  float s = v.x + v.y, ss = v.x * v.x + v.y * v.y;
  for (int o = 32; o; o >>= 1) { s += __shfl_down(s, o); ss += __shfl_down(ss, o); }
  __shared__ float ps[4], pss[4];
  int wave = threadIdx.x >> 6, lane = threadIdx.x & 63;
  if (!lane) { ps[wave] = s; pss[wave] = ss; }
  __syncthreads();
  s = ps[0] + ps[1] + ps[2] + ps[3];
  ss = pss[0] + pss[1] + pss[2] + pss[3];
  float mu = s * (1.f / DD);
  float var = ss * (1.f / DD) - mu * mu;
  float inv = rsqrtf(var + 1e-5f);
  int d = threadIdx.x * 2;
  out[(size_t)m * DD + d]     = __float2bfloat16((v.x - mu) * inv * g[d]     + bb[d]);
  out[(size_t)m * DD + d + 1] = __float2bfloat16((v.y - mu) * inv * g[d + 1] + bb[d + 1]);
}

// ---------------- fused conv+dt+local-scan (pass 1) ----------------
__global__ __launch_bounds__(128) void k_scan1f(
    const float* __restrict__ proj, const float* __restrict__ convw,
    const float* __restrict__ dtw, const float* __restrict__ dtb,
    float* __restrict__ ubuf, float* __restrict__ yloc,
    float* __restrict__ Ebuf, float* __restrict__ Aprod, float* __restrict__ hend)
{
  int d = (blockIdx.x << 7) + threadIdx.x;
  int c = blockIdx.y, b = blockIdx.z;
  int m0 = b * LSEQ + c * CH;
  __shared__ float sBC[CH][32];
  __shared__ float sDT[CH][32];
  for (int idx = threadIdx.x; idx < CH * 32; idx += 128) {
    int l = idx >> 5, j = idx & 31;
    sBC[l][j] = proj[(size_t)(m0 + l) * PW + 2 * DD + RR + j];
    sDT[l][j] = proj[(size_t)(m0 + l) * PW + 2 * DD + j];
  }
  __syncthreads();
  float cw0 = convw[d * 4], cw1 = convw[d * 4 + 1], cw2 = convw[d * 4 + 2], cw3 = convw[d * 4 + 3];
  float dtbd = dtb[d];
  f32x4 wr[8];
#pragma unroll
  for (int i = 0; i < 8; ++i) wr[i] = *(const f32x4*)(dtw + (size_t)d * RR + i * 4);
  float w0 = 0.f, w1 = 0.f, w2 = 0.f;
  {
    int l0 = c * CH;
    if (l0 >= 3) w0 = proj[(size_t)(m0 - 3) * PW + d];
    if (l0 >= 2) w1 = proj[(size_t)(m0 - 2) * PW + d];
    if (l0 >= 1) w2 = proj[(size_t)(m0 - 1) * PW + d];
  }
  float h[NST];
#pragma unroll
  for (int n = 0; n < NST; ++n) h[n] = 0.f;
  float S = 0.f;
  for (int l = 0; l < CH; ++l) {
    size_t m = (size_t)(m0 + l);
    float xc = proj[m * PW + d];
    float cv = w0 * cw0 + w1 * cw1 + w2 * cw2 + xc * cw3;
    w0 = w1; w1 = w2; w2 = xc;
    float uv = siluf(cv);
    ubuf[m * DD + d] = uv;
    float s = dtbd;
#pragma unroll
    for (int i = 0; i < 8; ++i) {
      f32x4 q = *(const f32x4*)&sDT[l][i * 4];
      s += q[0] * wr[i][0] + q[1] * wr[i][1] + q[2] * wr[i][2] + q[3] * wr[i][3];
    }
    float dtv = (s > 0.f) ? (s + log1pf(expf(-s))) : log1pf(expf(s));
    float e1 = expf(-dtv);
    S += dtv;
    Ebuf[m * DD + d] = expf(-S);
    float p = 1.f, acc = 0.f;
#pragma unroll
    for (int n = 0; n < NST; ++n) {
      p *= e1;
      float bu = (p - 1.f) * c_invn[n] * sBC[l][n] * uv;
      h[n] = p * h[n] + bu;
      acc += sBC[l][16 + n] * h[n];
    }
    yloc[m * DD + d] = acc;
  }
  float Ec = expf(-S);
  float p = 1.f;
  size_t base = ((size_t)(b * NCH + c) * NST) * DD + d;
#pragma unroll
  for (int n = 0; n < NST; ++n) {
    p *= Ec;
    Aprod[base + (size_t)n * DD] = p;
    hend [base + (size_t)n * DD] = h[n];
  }
}

// ---------------- scan pass 2: wave-parallel prefix over chunks ----------------
__global__ __launch_bounds__(256) void k_scan2w(
    const float* __restrict__ Aprod, const float* __restrict__ hend, float* __restrict__ h0)
{
  int wave = threadIdx.x >> 6, lane = threadIdx.x & 63;
  int chain = blockIdx.x * 4 + wave;          // b*8192 + n*512 + d
  int d = chain & 511;
  int n = (chain >> 9) & 15;
  int b = chain >> 13;
  size_t o = ((size_t)((b * NCH + lane) * NST + n)) * DD + d;
  float A = Aprod[o], h = hend[o];
#pragma unroll
  for (int off = 1; off < 64; off <<= 1) {
    float Ap = __shfl_up(A, off);
    float hp = __shfl_up(h, off);
    if (lane >= off) { h = A * hp + h; A = A * Ap; }
  }
  float hprev = __shfl_up(h, 1);
  h0[o] = (lane == 0) ? 0.f : hprev;
}

// ---------------- scan pass 3 + gate ----------------
__global__ __launch_bounds__(128) void k_scan3(
    const float* __restrict__ proj, const float* __restrict__ u,
    const float* __restrict__ yloc, const float* __restrict__ Ebuf,
    const float* __restrict__ h0, const float* __restrict__ Dp, bf16* __restrict__ out)
{
  int d = (blockIdx.x << 7) + threadIdx.x;
  int c = blockIdx.y, b = blockIdx.z;
  int m0 = b * LSEQ + c * CH;
  __shared__ float sC[CH][NST];
  for (int idx = threadIdx.x; idx < CH * NST; idx += 128)
    sC[idx >> 4][idx & 15] = proj[(size_t)(m0 + (idx >> 4)) * PW + 2 * DD + RR + NST + (idx & 15)];
  __syncthreads();
  float hh[NST];
  size_t base = ((size_t)(b * NCH + c) * NST) * DD + d;
#pragma unroll
  for (int n = 0; n < NST; ++n) hh[n] = h0[base + (size_t)n * DD];
  float dpv = Dp[d];
  for (int l = 0; l < CH; ++l) {
    size_t m = (size_t)(m0 + l);
    float E = Ebuf[m * DD + d];
    float p = 1.f, corr = 0.f;
#pragma unroll
    for (int n = 0; n < NST; ++n) {
      p *= E;
      corr += sC[l][n] * p * hh[n];
    }
    float y = yloc[m * DD + d] + corr;
    float z = proj[m * PW + DD + d];
    float v = (y + u[m * DD + d] * dpv) * siluf(z);
    out[m * DD + d] = __float2bfloat16(v);
  }
}

// ========= bf16 GEMMs: global_load_lds, BK=64 two-chunk staging =========
// 64x64 tile, BK=64: 4 gloads + 16 MFMA/wave per barrier drain. K%64==0.
template<int ACT, bool BF16OUT, bool RES, bool BIAS>
__global__ __launch_bounds__(256) void gemm_bb64k(
    const bf16* __restrict__ A, const bf16* __restrict__ B,
    const float* __restrict__ bias, const float* __restrict__ res,
    void* __restrict__ Cout, int N, int K)
{
  __shared__ bf16 sA[2][64 * 32];
  __shared__ bf16 sB[2][64 * 32];
  int flat = blockIdx.y * gridDim.x + blockIdx.x;
  int qq = (gridDim.x * gridDim.y) >> 3;
  int s = (flat & 7) * qq + (flat >> 3);
  int bm = (s % gridDim.x) * 64;
  int bn = (s / gridDim.x) * 64;
  int tid = threadIdx.x;
  int wave = tid >> 6, lane = tid & 63;
  int wm = (wave >> 1) << 5, wn = (wave & 1) << 5;
  int r = lane & 15, q = lane >> 4;
  int srow = (wave << 4) + (lane >> 2);
  int scol = (lane & 3) << 3;
  const bf16* pA = A + (size_t)(bm + srow) * K + scol;
  const bf16* pB = B + (size_t)(bn + srow) * K + scol;
  int lofs = (wave << 4) << 5;

  f32x4 acc[2][2];
#pragma unroll
  for (int i = 0; i < 2; ++i)
#pragma unroll
    for (int j = 0; j < 2; ++j) acc[i][j] = (f32x4){0.f, 0.f, 0.f, 0.f};

  for (int k0 = 0; k0 < K; k0 += 64) {
    gload16(pA,      sA[0] + lofs);
    gload16(pA + 32, sA[1] + lofs);
    gload16(pB,      sB[0] + lofs);
    gload16(pB + 32, sB[1] + lofs);
    pA += 64; pB += 64;
    __syncthreads();
#pragma unroll
    for (int kk = 0; kk < 2; ++kk) {
      s16x8 af[2], bg[2];
#pragma unroll
      for (int i = 0; i < 2; ++i) af[i] = *(s16x8*)&sA[kk][((wm + i * 16 + r) << 5) + (q << 3)];
#pragma unroll
      for (int j = 0; j < 2; ++j) bg[j] = *(s16x8*)&sB[kk][((wn + j * 16 + r) << 5) + (q << 3)];
#pragma unroll
      for (int i = 0; i < 2; ++i)
#pragma unroll
        for (int j = 0; j < 2; ++j)
          acc[i][j] = __builtin_amdgcn_mfma_f32_16x16x32_bf16(af[i], bg[j], acc[i][j], 0, 0, 0);
    }
    __syncthreads();
  }

#pragma unroll
  for (int i = 0; i < 2; ++i)
#pragma unroll
    for (int j = 0; j < 2; ++j) {
      int n = bn + wn + j * 16 + r;
#pragma unroll
      for (int e = 0; e < 4; ++e) {
        int m = bm + wm + i * 16 + (q << 2) + e;
        float v = acc[i][j][e];
        if (BIAS) v += bias[n];
        if (ACT == 1) v = 0.5f * v * (1.f + erff(v * 0.70710678118f));
        if (RES) v += res[(size_t)m * N + n];
        if (BF16OUT) ((bf16*)Cout)[(size_t)m * N + n] = __float2bfloat16(v);
        else         ((float*)Cout)[(size_t)m * N + n] = v;
      }
    }
}

// 128x128 tile, BK=64: 8 gloads + 32 MFMA/wave per barrier drain. K%64==0.
template<int ACT, bool BF16OUT, bool RES, bool BIAS>
__global__ __launch_bounds__(256) void gemm_bb128k(
    const bf16* __restrict__ A, const bf16* __restrict__ B,
    const float* __restrict__ bias, const float* __restrict__ res,
    void* __restrict__ Cout, int N, int K)
{
  __shared__ bf16 sA[2][128 * 32];
  __shared__ bf16 sB[2][128 * 32];
  int flat = blockIdx.y * gridDim.x + blockIdx.x;
  int qq = (gridDim.x * gridDim.y) >> 3;
  int s = (flat & 7) * qq + (flat >> 3);
  int bm = (s % gridDim.x) * 128;
  int bn = (s / gridDim.x) * 128;
  int tid = threadIdx.x;
  int wave = tid >> 6, lane = tid & 63;
  int wm = (wave >> 1) << 6, wn = (wave & 1) << 6;
  int r = lane & 15, q = lane >> 4;
  int srow = (wave << 4) + (lane >> 2);
  int scol = (lane & 3) << 3;
  const bf16* pA = A + (size_t)(bm + srow) * K + scol;
  const bf16* pB = B + (size_t)(bn + srow) * K + scol;
  int lofs = (wave << 4) << 5;

  f32x4 acc[4][4];
#pragma unroll
  for (int i = 0; i < 4; ++i)
#pragma unroll
    for (int j = 0; j < 4; ++j) acc[i][j] = (f32x4){0.f, 0.f, 0.f, 0.f};

  for (int k0 = 0; k0 < K; k0 += 64) {
    gload16(pA,                       sA[0] + lofs);
    gload16(pA + (size_t)64 * K,      sA[0] + lofs + 64 * 32);
    gload16(pA + 32,                  sA[1] + lofs);
    gload16(pA + (size_t)64 * K + 32, sA[1] + lofs + 64 * 32);
    gload16(pB,                       sB[0] + lofs);
    gload16(pB + (size_t)64 * K,      sB[0] + lofs + 64 * 32);
    gload16(pB + 32,                  sB[1] + lofs);
    gload16(pB + (size_t)64 * K + 32, sB[1] + lofs + 64 * 32);
    pA += 64; pB += 64;
    __syncthreads();
#pragma unroll
    for (int kk = 0; kk < 2; ++kk) {
      s16x8 af[4], bg[4];
#pragma unroll
      for (int i = 0; i < 4; ++i) af[i] = *(s16x8*)&sA[kk][((wm + i * 16 + r) << 5) + (q << 3)];
#pragma unroll
      for (int j = 0; j < 4; ++j) bg[j] = *(s16x8*)&sB[kk][((wn + j * 16 + r) << 5) + (q << 3)];
#pragma unroll
      for (int i = 0; i < 4; ++i)
#pragma unroll
        for (int j = 0; j < 4; ++j)
          acc[i][j] = __builtin_amdgcn_mfma_f32_16x16x32_bf16(af[i], bg[j], acc[i][j], 0, 0, 0);
    }
    __syncthreads();
  }

#pragma unroll
  for (int i = 0; i < 4; ++i)
#pragma unroll
    for (int j = 0; j < 4; ++j) {
      int n = bn + wn + j * 16 + r;
      if (n >= N) continue;
#pragma unroll
      for (int e = 0; e < 4; ++e) {
        int m = bm + wm + i * 16 + (q << 2) + e;
        float v = acc[i][j][e];
        if (BIAS) v += bias[n];
        if (ACT == 1) v = 0.5f * v * (1.f + erff(v * 0.70710678118f));
        if (RES) v += res[(size_t)m * N + n];
        if (BF16OUT) ((bf16*)Cout)[(size_t)m * N + n] = __float2bfloat16(v);
        else         ((float*)Cout)[(size_t)m * N + n] = v;
      }
    }
}

// ================= fallback f32-weight GEMMs =================
template<int ACT, bool BF16OUT, bool RES, bool BIAS, bool SWZ>
__global__ __launch_bounds__(256) void gemm_abt(
    const bf16* __restrict__ A, const float* __restrict__ B,
    const float* __restrict__ bias, const float* __restrict__ res,
    void* __restrict__ Cout, int N, int K)
{
  __shared__ bf16 sA[128][PAD];
  __shared__ bf16 sB[128][PAD];
  int bn, bm;
  if (SWZ) {
    int flat = blockIdx.y * gridDim.x + blockIdx.x;
    int q = (gridDim.x * gridDim.y) >> 3;
    int s = (flat & 7) * q + (flat >> 3);
    bm = (s % gridDim.x) * 128;
    bn = (s / gridDim.x) * 128;
  } else {
    bn = blockIdx.x * 128;
    bm = blockIdx.y * 128;
  }
  int tid = threadIdx.x;
  int wave = tid >> 6, lane = tid & 63;
  int wm = (wave >> 1) << 6, wn = (wave & 1) << 6;
  int r = lane & 15, q = lane >> 4;
  int ldr = tid >> 2;
  int ldc = (tid & 3) << 3;
  f32x4 acc[4][4];
#pragma unroll
  for (int i = 0; i < 4; ++i)
#pragma unroll
    for (int j = 0; j < 4; ++j) acc[i][j] = (f32x4){0.f, 0.f, 0.f, 0.f};
  s16x8 pa[2];
  f32x4 pb[2][2];
#define GLOAD(k0)                                                              \
  {                                                                            \
    _Pragma("unroll")                                                          \
    for (int h = 0; h < 2; ++h) {                                              \
      int row = ldr + (h << 6);                                                \
      pa[h] = *(const s16x8*)(A + (size_t)(bm + row) * K + (k0) + ldc);        \
      int nrow = bn + row;                                                     \
      if (nrow < N) {                                                          \
        const float* src = B + (size_t)nrow * K + (k0) + ldc;                  \
        pb[h][0] = *(const f32x4*)src;                                         \
        pb[h][1] = *(const f32x4*)(src + 4);                                   \
      } else {                                                                 \
        pb[h][0] = (f32x4){0.f,0.f,0.f,0.f};                                   \
        pb[h][1] = (f32x4){0.f,0.f,0.f,0.f};                                   \
      }                                                                        \
    }                                                                          \
  }
  GLOAD(0);
  for (int k0 = 0; k0 < K; k0 += 32) {
#pragma unroll
    for (int h = 0; h < 2; ++h) {
      int row = ldr + (h << 6);
      *(s16x8*)&sA[row][ldc] = pa[h];
      *(s16x8*)&sB[row][ldc] = cvt8(pb[h][0], pb[h][1]);
    }
    __syncthreads();
    if (k0 + 32 < K) GLOAD(k0 + 32);
    s16x8 af[4], bg[4];
#pragma unroll
    for (int i = 0; i < 4; ++i) af[i] = *(s16x8*)&sA[wm + i * 16 + r][q << 3];
#pragma unroll
    for (int j = 0; j < 4; ++j) bg[j] = *(s16x8*)&sB[wn + j * 16 + r][q << 3];
#pragma unroll
    for (int i = 0; i < 4; ++i)
#pragma unroll
      for (int j = 0; j < 4; ++j)
        acc[i][j] = __builtin_amdgcn_mfma_f32_16x16x32_bf16(af[i], bg[j], acc[i][j], 0, 0, 0);
    __syncthreads();
  }
#undef GLOAD
#pragma unroll
  for (int i = 0; i < 4; ++i)
#pragma unroll
    for (int j = 0; j < 4; ++j) {
      int n = bn + wn + j * 16 + r;
      if (n >= N) continue;
#pragma unroll
      for (int e = 0; e < 4; ++e) {
        int m = bm + wm + i * 16 + (q << 2) + e;
        float v = acc[i][j][e];
        if (BIAS) v += bias[n];
        if (ACT == 1) v = 0.5f * v * (1.f + erff(v * 0.70710678118f));
        if (RES) v += res[(size_t)m * N + n];
        if (BF16OUT) ((bf16*)Cout)[(size_t)m * N + n] = __float2bfloat16(v);
        else         ((float*)Cout)[(size_t)m * N + n] = v;
      }
    }
}

template<int ACT, bool BF16OUT, bool RES, bool BIAS>
__global__ __launch_bounds__(256) void gemm64(
    const bf16* __restrict__ A, const float* __restrict__ B,
    const float* __restrict__ bias, const float* __restrict__ res,
    void* __restrict__ Cout, int N, int K)
{
  __shared__ bf16 sA[64][PAD];
  __shared__ bf16 sB[64][PAD];
  int bn = blockIdx.x * 64;
  int bm = blockIdx.y * 64;
  int tid = threadIdx.x;
  int wave = tid >> 6, lane = tid & 63;
  int wm = (wave >> 1) << 5, wn = (wave & 1) << 5;
  int r = lane & 15, q = lane >> 4;
  int ldr = tid >> 2;
  int ldc = (tid & 3) << 3;
  f32x4 acc[2][2];
#pragma unroll
  for (int i = 0; i < 2; ++i)
#pragma unroll
    for (int j = 0; j < 2; ++j) acc[i][j] = (f32x4){0.f, 0.f, 0.f, 0.f};
  s16x8 pa;
  f32x4 pb[2];
#define GLOAD64(k0)                                                            \
  {                                                                            \
    pa = *(const s16x8*)(A + (size_t)(bm + ldr) * K + (k0) + ldc);             \
    const float* src = B + (size_t)(bn + ldr) * K + (k0) + ldc;                \
    pb[0] = *(const f32x4*)src;                                                \
    pb[1] = *(const f32x4*)(src + 4);                                          \
  }
  GLOAD64(0);
  for (int k0 = 0; k0 < K; k0 += 32) {
    *(s16x8*)&sA[ldr][ldc] = pa;
    *(s16x8*)&sB[ldr][ldc] = cvt8(pb[0], pb[1]);
    __syncthreads();
    if (k0 + 32 < K) GLOAD64(k0 + 32);
    s16x8 af[2], bg[2];
#pragma unroll
    for (int i = 0; i < 2; ++i) af[i] = *(s16x8*)&sA[wm + i * 16 + r][q << 3];
#pragma unroll
    for (int j = 0; j < 2; ++j) bg[j] = *(s16x8*)&sB[wn + j * 16 + r][q << 3];
#pragma unroll
    for (int i = 0; i < 2; ++i)
#pragma unroll
      for (int j = 0; j < 2; ++j)
        acc[i][j] = __builtin_amdgcn_mfma_f32_16x16x32_bf16(af[i], bg[j], acc[i][j], 0, 0, 0);
    __syncthreads();
  }
#undef GLOAD64
#pragma unroll
  for (int i = 0; i < 2; ++i)
#pragma unroll
    for (int j = 0; j < 2; ++j) {
      int n = bn + wn + j * 16 + r;
#pragma unroll
      for (int e = 0; e < 4; ++e) {
        int m = bm + wm + i * 16 + (q << 2) + e;
        float v = acc[i][j][e];
        if (BIAS) v += bias[n];
        if (ACT == 1) v = 0.5f * v * (1.f + erff(v * 0.70710678118f));
        if (RES) v += res[(size_t)m * N + n];
        if (BF16OUT) ((bf16*)Cout)[(size_t)m * N + n] = __float2bfloat16(v);
        else         ((float*)Cout)[(size_t)m * N + n] = v;
      }
    }
}

// ---------------- launch ----------------
extern "C" void kernel_launch(void* const* d_in, const int* in_sizes, int n_in,
                              void* d_out, int out_size, void* d_ws, size_t ws_size,
                              hipStream_t stream) {
  const int*   x_t     = (const int*)d_in[0];
  const int*   t       = (const int*)d_in[1];
  const float* tok_emb = (const float*)d_in[2];
  const float* tmlp_w1 = (const float*)d_in[3];
  const float* tmlp_b1 = (const float*)d_in[4];
  const float* tmlp_w2 = (const float*)d_in[5];
  const float* tmlp_b2 = (const float*)d_in[6];
  const float* ln1_g   = (const float*)d_in[7];
  const float* ln1_b   = (const float*)d_in[8];
  const float* in_w    = (const float*)d_in[9];
  const float* conv_w  = (const float*)d_in[10];
  const float* dt_w    = (const float*)d_in[11];
  const float* dt_b    = (const float*)d_in[12];
  const float* D_p     = (const float*)d_in[13];
  const float* out_w   = (const float*)d_in[14];
  const float* ln2_g   = (const float*)d_in[15];
  const float* ln2_b   = (const float*)d_in[16];
  const float* mlp_w1  = (const float*)d_in[17];
  const float* mlp_b1  = (const float*)d_in[18];
  const float* mlp_w2  = (const float*)d_in[19];
  const float* mlp_b2  = (const float*)d_in[20];
  const float* lno_g   = (const float*)d_in[21];
  const float* lno_b   = (const float*)d_in[22];
  const float* head_w  = (const float*)d_in[23];
  const float* head_b  = (const float*)d_in[24];

  char* w = (char*)d_ws;
  float* te    = (float*)w;  w += 4096;
  float* h1t   = (float*)w;  w += 16384;
  float* x     = (float*)w;  w += (size_t)M_TOK * DD * 4;
  bf16*  aIn   = (bf16*)w;   w += (size_t)M_TOK * DD * 2;
  float* proj  = (float*)w;  w += (size_t)M_TOK * PW * 4;
  float* ubuf  = (float*)w;  w += (size_t)M_TOK * DD * 4;
  float* ybuf  = (float*)w;  w += (size_t)M_TOK * DD * 4;
  float* Ebuf  = (float*)w;  w += (size_t)M_TOK * DD * 4;
  float* Aprod = (float*)w;  w += (size_t)2 * NCH * NST * DD * 4;
  float* hend  = (float*)w;  w += (size_t)2 * NCH * NST * DD * 4;
  float* h0    = (float*)w;  w += (size_t)2 * NCH * NST * DD * 4;
  bf16*  gbuf  = (bf16*)proj;
  bf16* bw_in   = (bf16*)w;  w += (size_t)6 * PW * DD * 2;
  bf16* bw_out  = (bf16*)w;  w += (size_t)6 * DD * DD * 2;
  bf16* bw_m1   = (bf16*)w;  w += (size_t)6 * DFFW * DD * 2;
  bf16* bw_m2   = (bf16*)w;  w += (size_t)6 * DD * DFFW * 2;
  bf16* bw_head = (bf16*)w;  w += (size_t)NHEADP * DD * 2;
  bool fast = ((size_t)(w - (char*)d_ws) <= ws_size);

  if (fast) {
    k_cvt<<<1024, 256, 0, stream>>>(in_w,   bw_in,   6 * PW * DD,   6 * PW * DD);
    k_cvt<<<1024, 256, 0, stream>>>(out_w,  bw_out,  6 * DD * DD,   6 * DD * DD);
    k_cvt<<<1024, 256, 0, stream>>>(mlp_w1, bw_m1,   6 * DFFW * DD, 6 * DFFW * DD);
    k_cvt<<<1024, 256, 0, stream>>>(mlp_w2, bw_m2,   6 * DD * DFFW, 6 * DD * DFFW);
    k_cvt<<<2048, 256, 0, stream>>>(head_w, bw_head, NHEAD * DD,    NHEADP * DD);
  }

  k_te1<<<512, 256, 0, stream>>>(t, tmlp_w1, tmlp_b1, h1t);
  k_te2<<<128, 256, 0, stream>>>(h1t, tmlp_w2, tmlp_b2, te);
  k_embed<<<M_TOK, 256, 0, stream>>>(x_t, tok_emb, te, x);

  for (int i = 0; i < 6; ++i) {
    const float* cw_i   = conv_w + (size_t)i * DD * 4;
    const float* dtw_i  = dt_w   + (size_t)i * DD * RR;
    const float* dtb_i  = dt_b   + (size_t)i * DD;
    const float* dp_i   = D_p    + (size_t)i * DD;
    const float* m1b_i  = mlp_b1 + (size_t)i * DFFW;
    const float* m2b_i  = mlp_b2 + (size_t)i * DD;

    k_layernorm<<<M_TOK, 256, 0, stream>>>(x, ln1_g + i * DD, ln1_b + i * DD, aIn);
    if (fast)
      gemm_bb64k<0,false,false,false><<<dim3(M_TOK / 64, PW / 64), 256, 0, stream>>>(
          aIn, bw_in + (size_t)i * PW * DD, nullptr, nullptr, proj, PW, DD);
    else
      gemm64<0,false,false,false><<<dim3(PW / 64, M_TOK / 64), 256, 0, stream>>>(
          aIn, in_w + (size_t)i * PW * DD, nullptr, nullptr, proj, PW, DD);
    k_scan1f<<<dim3(4, NCH, 2), 128, 0, stream>>>(proj, cw_i, dtw_i, dtb_i,
                                                  ubuf, ybuf, Ebuf, Aprod, hend);
    k_scan2w<<<2 * NST * DD / 4, 256, 0, stream>>>(Aprod, hend, h0);
    k_scan3<<<dim3(4, NCH, 2), 128, 0, stream>>>(proj, ubuf, ybuf, Ebuf, h0, dp_i, aIn);
    if (fast) {
      gemm_bb64k<0,false,true,false><<<dim3(M_TOK / 64, DD / 64), 256, 0, stream>>>(
          aIn, bw_out + (size_t)i * DD * DD, nullptr, x, x, DD, DD);
      k_layernorm<<<M_TOK, 256, 0, stream>>>(x, ln2_g + i * DD, ln2_b + i * DD, aIn);
      gemm_bb64k<1,true,false,true><<<dim3(M_TOK / 64, DFFW / 64), 256, 0, stream>>>(
          aIn, bw_m1 + (size_t)i * DFFW * DD, m1b_i, nullptr, gbuf, DFFW, DD);
      gemm_bb64k<0,false,true,true><<<dim3(M_TOK / 64, DD / 64), 256, 0, stream>>>(
          gbuf, bw_m2 + (size_t)i * DD * DFFW, m2b_i, x, x, DD, DFFW);
    } else {
      gemm64<0,false,true,false><<<dim3(DD / 64, M_TOK / 64), 256, 0, stream>>>(
          aIn, out_w + (size_t)i * DD * DD, nullptr, x, x, DD, DD);
      k_layernorm<<<M_TOK, 256, 0, stream>>>(x, ln2_g + i * DD, ln2_b + i * DD, aIn);
      gemm64<1,true,false,true><<<dim3(DFFW / 64, M_TOK / 64), 256, 0, stream>>>(
          aIn, mlp_w1 + (size_t)i * DFFW * DD, m1b_i, nullptr, gbuf, DFFW, DD);
      gemm64<0,false,true,true><<<dim3(DD / 64, M_TOK / 64), 256, 0, stream>>>(
          gbuf, mlp_w2 + (size_t)i * DD * DFFW, m2b_i, x, x, DD, DFFW);
    }
  }

  k_layernorm<<<M_TOK, 256, 0, stream>>>(x, lno_g, lno_b, aIn);
  if (fast)
    gemm_bb128k<0,false,false,true><<<dim3(M_TOK / 128, NHEADP / 128), 256, 0, stream>>>(
        aIn, bw_head, head_b, nullptr, d_out, NHEAD, DD);
  else
    gemm_abt<0,false,false,true,true><<<dim3(M_TOK / 128, (NHEAD + 127) / 128), 256, 0, stream>>>(
        aIn, head_w, head_b, nullptr, d_out, NHEAD, DD);
}